// Round 7
// baseline (287.836 us; speedup 1.0000x reference)
//
#include <hip/hip_runtime.h>
#include <hip/hip_bf16.h>

typedef __hip_bfloat16 bf16;
typedef __attribute__((ext_vector_type(2))) float fl2;
typedef __attribute__((ext_vector_type(8))) short bfx8;
typedef __attribute__((ext_vector_type(4))) short bfx4;
typedef __attribute__((ext_vector_type(4))) float fx4;
typedef __attribute__((ext_vector_type(4))) int ix4;
typedef __attribute__((ext_vector_type(2))) int ix2;

#define KD 384
#define CH 384

__device__ __forceinline__ float bf2f(bf16 v) { return __bfloat162float(v); }
__device__ __forceinline__ bf16 f2bf(float v) { return __float2bfloat16(v); }
__device__ __forceinline__ int pk2(float x, float y) {
    return (int)(((unsigned)__bfloat16_as_ushort(__float2bfloat16(y)) << 16) |
                 (unsigned)__bfloat16_as_ushort(__float2bfloat16(x)));
}
__device__ __forceinline__ float lo16(int u) { return __uint_as_float((unsigned)u << 16); }
__device__ __forceinline__ float hi16(int u) { return __uint_as_float((unsigned)u & 0xffff0000u); }

typedef const __attribute__((address_space(1))) void gvoid;
typedef __attribute__((address_space(3))) void lvoid;
__device__ __forceinline__ void gload16(const void* g, void* l) {
    __builtin_amdgcn_global_load_lds((gvoid*)g, (lvoid*)l, 16, 0, 0);
}

// ---------------------------------------------------------------------------
// cast: fp32 -> bf16 for [x | q_w | kv_w | proj_w] into one contiguous span.
// ---------------------------------------------------------------------------
__global__ __launch_bounds__(256) void cast_kernel(
    const float* __restrict__ x, const float* __restrict__ qw,
    const float* __restrict__ kvw, const float* __restrict__ pw,
    bf16* __restrict__ dst)
{
    const int i = blockIdx.x * 256 + threadIdx.x;   // float4 index
    const float* s; int off;
    if (i < 3145728)      { s = x;   off = i; }
    else if (i < 3182592) { s = qw;  off = i - 3145728; }
    else if (i < 3256320) { s = kvw; off = i - 3182592; }
    else                  { s = pw;  off = i - 3256320; }
    const fx4 v = *(const fx4*)(s + (size_t)off * 4);
    const ix2 p = (ix2){pk2(v[0], v[1]), pk2(v[2], v[3])};
    *(ix2*)(void*)(dst + (size_t)i * 4) = p;
}

// ---------------------------------------------------------------------------
// GEMM (bf16, m97 structure): C[r,oc] = sum_k A[r,k]*B[oc,k] + bias[oc]
// MODE 0: B = [q_w;kv_w]; epilogue LDS-transpose -> qkv2[b][dd][t] bf16
// MODE 1: B = proj_w; fp32 store [r][oc] to d_out.
// ---------------------------------------------------------------------------
template <int MODE>
__global__ __launch_bounds__(256) void gemm_tile(
    const bf16* __restrict__ A, const bf16* __restrict__ B0,
    const bf16* __restrict__ B1, const float* __restrict__ bias0,
    const float* __restrict__ bias1, void* __restrict__ outv)
{
    constexpr int NT = (MODE == 0) ? 9 : 3;
    const int tid  = threadIdx.x;
    const int wave = tid >> 6, lane = tid & 63;

    const int f = blockIdx.x;
    const int xcd = f & 7, idx = f >> 3;
    const int mi = idx / NT, nt = idx - mi * NT;
    const int m0 = (xcd + (mi << 3)) * 128;
    const int n0 = nt * 128;

    const bf16* Bsrc;
    const float* bsrc;
    int boff;
    if constexpr (MODE == 0) {
        if (n0 >= CH) { Bsrc = B1 + (size_t)(n0 - CH) * KD; bsrc = bias1; boff = n0 - CH; }
        else          { Bsrc = B0 + (size_t)n0 * KD;        bsrc = bias0; boff = n0; }
    } else {
        Bsrc = B0 + (size_t)n0 * KD; bsrc = bias0; boff = n0;
    }

    const int wm = (wave & 1) * 64, wn = (wave >> 1) * 64;
    const int r16 = lane & 15, quad = lane >> 4;
    const int sr = lane >> 2, sseg = lane & 3;

    constexpr int SMEM = (MODE == 0) ? 17408 : 16384;
    __shared__ __align__(16) char smem[SMEM];
    bf16* As = (bf16*)smem;             // 128*32
    bf16* Bs = (bf16*)(smem + 8192);    // 128*32

    fx4 acc[4][4];
#pragma unroll
    for (int i = 0; i < 4; ++i)
#pragma unroll
        for (int j = 0; j < 4; ++j) acc[i][j] = (fx4){0.f, 0.f, 0.f, 0.f};

    for (int kt = 0; kt < KD; kt += 32) {
        __syncthreads();
#pragma unroll
        for (int ii = 0; ii < 2; ++ii) {
            const int c = ii * 4 + wave;
            const int r = c * 16 + sr;
            gload16(A + (size_t)(m0 + r) * KD + kt + sseg * 8, (char*)As + c * 1024);
            gload16(Bsrc + (size_t)r * KD + kt + sseg * 8, (char*)Bs + c * 1024);
        }
        __syncthreads();   // vmcnt(0) drain: async loads landed

        bfx8 af[4], bfr[4];
#pragma unroll
        for (int t = 0; t < 4; ++t) {
            af[t]  = *(const bfx8*)(const void*)(As + (wm + t * 16 + r16) * 32 + quad * 8);
            bfr[t] = *(const bfx8*)(const void*)(Bs + (wn + t * 16 + r16) * 32 + quad * 8);
        }
#pragma unroll
        for (int i = 0; i < 4; ++i)
#pragma unroll
            for (int j = 0; j < 4; ++j)
                acc[i][j] = __builtin_amdgcn_mfma_f32_16x16x32_bf16(
                    af[i], bfr[j], acc[i][j], 0, 0, 0);
    }

    if constexpr (MODE == 0) {
        // epilogue: bias + transpose through LDS, store [b][dd][g][m] bf16
        bf16* tr = (bf16*)smem;   // 64*136 (overlays As/Bs; barrier-protected)
        const int bb = m0 >> 12, mbase = m0 & 4095;
#pragma unroll
        for (int half = 0; half < 2; ++half) {
            __syncthreads();   // prev readers (K-loop or half 0) done
            if ((wave >> 1) == half) {
#pragma unroll
                for (int j = 0; j < 4; ++j) {
                    const int ocl = j * 16 + r16;                 // 0..63 in half
                    const float bv = bsrc[boff + wn + j * 16 + r16];
#pragma unroll
                    for (int i = 0; i < 4; ++i) {
                        const int m_loc = wm + i * 16 + quad * 4;
                        const ix2 pr = (ix2){
                            pk2(acc[i][j][0] + bv, acc[i][j][1] + bv),
                            pk2(acc[i][j][2] + bv, acc[i][j][3] + bv)};
                        *(ix2*)(void*)(tr + ocl * 136 + m_loc) = pr;
                    }
                }
            }
            __syncthreads();
            bf16* outp = (bf16*)outv;
            for (int u = tid; u < 1024; u += 256) {
                const int ocl = u >> 4, seg = u & 15;
                const int oc = n0 + half * 64 + ocl;
                const int g = oc >> 6, dd = oc & 63;
                const ix4 val = *(const ix4*)(const void*)(tr + ocl * 136 + seg * 8);
                const size_t dst = (((size_t)(bb * 64 + dd)) * 18 + g) * 4096 + mbase + seg * 8;
                *(ix4*)(void*)(outp + dst) = val;
            }
        }
    } else {
#pragma unroll
        for (int j = 0; j < 4; ++j) {
            const int oc = n0 + wn + j * 16 + r16;
            const float bv = bsrc[boff + wn + j * 16 + r16];
#pragma unroll
            for (int i = 0; i < 4; ++i) {
#pragma unroll
                for (int v = 0; v < 4; ++v) {
                    const int r = m0 + wm + i * 16 + quad * 4 + v;
                    ((float*)outv)[(size_t)r * CH + oc] = acc[i][j][v] + bv;
                }
            }
        }
    }
}

// ---------------------------------------------------------------------------
// fused fc + grouped 3x3 conv.  (Round-1 verified numerics: bf16 img, fp32
// weights, scalar unpack.)  The conv inner loop is expressed as float2
// element-wise math so the compiler may lower to v_pk_fma_f32 (2 FMA/instr,
// packed fp32) -- bit-compatible with the scalar form, perf-speculative.
// qkv2[b][dd][t] (t = n*18+i gives the 18 fc inputs of pixel n CONTIGUOUS).
// ---------------------------------------------------------------------------
__global__ __launch_bounds__(256) void fcconv_kernel(
    const bf16* __restrict__ qkv2, const float* __restrict__ fc_w,
    const float* __restrict__ fc_b, const float* __restrict__ dep_w,
    const float* __restrict__ dep_b, bf16* __restrict__ cvo)
{
    const int tid = threadIdx.x;
    const int q = blockIdx.x, dd = blockIdx.y, b = blockIdx.z;
    const int h0 = q * 16;

    __shared__ bf16 img[9 * 18 * 68];   // 22032 B

    const bf16* qb = qkv2 + ((size_t)(b * 64 + dd)) * 73728;

    // ---- fc phase: 18 rows x 66 cols (halo) ----
    for (int p = tid; p < 18 * 66; p += 256) {
        const int r = p / 66, cc = p - r * 66;
        const int h = h0 - 1 + r, wg = cc - 1;
        float s[9];
        if (h >= 0 && h < 64 && wg >= 0 && wg < 64) {
            const int n = h * 64 + wg;
            const int* tp = (const int*)(const void*)(qb + (size_t)n * 18);
            float xv[18];
#pragma unroll
            for (int k = 0; k < 9; ++k) {
                const int u = tp[k];
                xv[2 * k]     = lo16(u);
                xv[2 * k + 1] = hi16(u);
            }
#pragma unroll
            for (int o = 0; o < 9; ++o) {
                float t = fc_b[o];
#pragma unroll
                for (int i = 0; i < 18; ++i) t += fc_w[o * 18 + i] * xv[i];
                s[o] = t;
            }
        } else {
#pragma unroll
            for (int o = 0; o < 9; ++o) s[o] = 0.f;
        }
#pragma unroll
        for (int o = 0; o < 9; ++o) img[(o * 18 + r) * 68 + cc] = f2bf(s[o]);
    }
    __syncthreads();

    // ---- conv phase (float2 packed fp32) ----
    const int r_out = tid >> 4;          // 0..15
    const int w0 = (tid & 15) * 4;       // 0..60

    fl2 acc2[6][2];                      // [oc][{(w0,w1),(w2,w3)}]
#pragma unroll
    for (int oc = 0; oc < 6; ++oc) {
        const float bv = dep_b[dd * 6 + oc];
        acc2[oc][0] = (fl2){bv, bv};
        acc2[oc][1] = (fl2){bv, bv};
    }

    const float* wbase = dep_w + (size_t)dd * 486;
    for (int j = 0; j < 9; ++j) {
        float wj[6][9];
#pragma unroll
        for (int oc = 0; oc < 6; ++oc)
#pragma unroll
            for (int t = 0; t < 9; ++t) wj[oc][t] = wbase[oc * 81 + j * 9 + t];
#pragma unroll
        for (int dy = 0; dy < 3; ++dy) {
            const bf16* rp = img + (j * 18 + r_out + dy) * 68 + w0;
            const ix2 d01 = *(const ix2*)(const void*)rp;
            const int d2 = *(const int*)(const void*)(rp + 4);
            const float x0 = lo16(d01[0]), x1 = hi16(d01[0]);
            const float x2 = lo16(d01[1]), x3 = hi16(d01[1]);
            const float x4 = lo16(d2),     x5 = hi16(d2);
            const fl2 X01 = {x0, x1}, X12 = {x1, x2}, X23 = {x2, x3};
            const fl2 X34 = {x3, x4}, X45 = {x4, x5};
#pragma unroll
            for (int oc = 0; oc < 6; ++oc) {
                const float k0 = wj[oc][dy * 3], k1 = wj[oc][dy * 3 + 1], k2 = wj[oc][dy * 3 + 2];
                const fl2 K0 = {k0, k0}, K1 = {k1, k1}, K2 = {k2, k2};
                acc2[oc][0] += K0 * X01 + K1 * X12 + K2 * X23;
                acc2[oc][1] += K0 * X23 + K1 * X34 + K2 * X45;
            }
        }
    }

#pragma unroll
    for (int oc = 0; oc < 6; ++oc) {
        const size_t base =
            ((size_t)(b * 384 + dd * 6 + oc)) * 4096 + (h0 + r_out) * 64 + w0;
        const ix2 pr = (ix2){pk2(acc2[oc][0][0], acc2[oc][0][1]),
                             pk2(acc2[oc][1][0], acc2[oc][1][1])};
        *(ix2*)(void*)(cvo + base) = pr;
    }
}

// ---------------------------------------------------------------------------
// LayerNorm over C + exact GELU; reads [b][oc][n] bf16, writes [b][n][c] bf16
// ---------------------------------------------------------------------------
__global__ __launch_bounds__(256) void ln_gelu_kernel(
    const bf16* __restrict__ cvo, const float* __restrict__ ln_g,
    const float* __restrict__ ln_b, bf16* __restrict__ gel)
{
    const int tid = threadIdx.x;
    const int n0 = blockIdx.x * 32;
    const int b  = blockIdx.y;

    __shared__ float tile[384 * 33];
    __shared__ float ps[32 * 9], pq[32 * 9];
    __shared__ float mu_s[32], inv_s[32];

    const bf16* src = cvo + (size_t)b * 384 * 4096;
    for (int v = tid; v < 384 * 8; v += 256) {
        const int oc = v >> 3, j = v & 7;   // j indexes 4-wide n chunks
        const ix2 d = *(const ix2*)(const void*)(src + (size_t)oc * 4096 + n0 + j * 4);
        float* tp = tile + oc * 33 + j * 4;
        tp[0] = lo16(d[0]); tp[1] = hi16(d[0]);
        tp[2] = lo16(d[1]); tp[3] = hi16(d[1]);
    }
    __syncthreads();

    {
        const int nl = tid & 31, sl = tid >> 5;
        float s = 0.f, q = 0.f;
        for (int oc = sl * 48; oc < sl * 48 + 48; ++oc) {
            const float xv = tile[oc * 33 + nl];
            s += xv; q += xv * xv;
        }
        ps[nl * 9 + sl] = s; pq[nl * 9 + sl] = q;
    }
    __syncthreads();
    if (tid < 32) {
        float s = 0.f, q = 0.f;
        for (int k = 0; k < 8; ++k) { s += ps[tid * 9 + k]; q += pq[tid * 9 + k]; }
        const float mu = s * (1.f / 384.f);
        const float var = q * (1.f / 384.f) - mu * mu;
        mu_s[tid] = mu; inv_s[tid] = rsqrtf(var + 1e-5f);
    }
    __syncthreads();

    for (int v = tid; v < 192 * 32; v += 256) {
        const int oc2 = v % 192, nl = v / 192;
        const int oc = oc2 * 2;
        const float mu = mu_s[nl], inv = inv_s[nl];
        const float x0 = tile[oc * 33 + nl];
        const float x1 = tile[(oc + 1) * 33 + nl];
        const float y0 = (x0 - mu) * inv * ln_g[oc] + ln_b[oc];
        const float y1 = (x1 - mu) * inv * ln_g[oc + 1] + ln_b[oc + 1];
        const float g0 = 0.5f * y0 * (1.f + erff(y0 * 0.70710678118f));
        const float g1 = 0.5f * y1 * (1.f + erff(y1 * 0.70710678118f));
        *(int*)(void*)(gel + ((size_t)b * 4096 + n0 + nl) * 384 + oc) = pk2(g0, g1);
    }
}

// ---------------------------------------------------------------------------
extern "C" void kernel_launch(void* const* d_in, const int* in_sizes, int n_in,
                              void* d_out, int out_size, void* d_ws, size_t ws_size,
                              hipStream_t stream)
{
    const float* x      = (const float*)d_in[0];
    const float* q_w    = (const float*)d_in[1];
    const float* q_b    = (const float*)d_in[2];
    const float* kv_w   = (const float*)d_in[3];
    const float* kv_b   = (const float*)d_in[4];
    const float* fc_w   = (const float*)d_in[5];
    const float* fc_b   = (const float*)d_in[6];
    const float* dep_w  = (const float*)d_in[7];
    const float* dep_b  = (const float*)d_in[8];
    const float* ln_g   = (const float*)d_in[9];
    const float* ln_b   = (const float*)d_in[10];
    const float* proj_w = (const float*)d_in[11];
    const float* proj_b = (const float*)d_in[12];

    // workspace (total 152,174,592 B):
    char* ws = (char*)d_ws;
    bf16*  castspan = (bf16*)ws;                    // 26,345,472 B
    bf16*  xb     = castspan;
    bf16*  qwb    = castspan + 12582912;
    bf16*  kvwb   = castspan + 12730368;
    bf16*  projwb = castspan + 13025280;
    bf16*  qkv2   = (bf16*)(ws + 26345472);         // 75,497,472 B  [b][dd][t]
    bf16*  cvo    = (bf16*)(ws + 101842944);        // 25,165,824 B  [b][oc][n]
    bf16*  gel    = (bf16*)(ws + 127008768);        // 25,165,824 B  [b][n][c]

    // 0) fp32 -> bf16 cast of x and the GEMM weight matrices
    cast_kernel<<<dim3(12864), 256, 0, stream>>>(x, q_w, kv_w, proj_w, castspan);
    // 1) qkv2 = X @ [q_w;kv_w]^T + bias, transposed store [b][dd][t]
    gemm_tile<0><<<dim3(2304), 256, 0, stream>>>(xb, qwb, kvwb, q_b, kv_b, qkv2);
    // 2) fused fc + grouped 3x3 conv -> bf16 [b][oc][n]
    fcconv_kernel<<<dim3(4, 64, 8), 256, 0, stream>>>(qkv2, fc_w, fc_b, dep_w,
                                                      dep_b, cvo);
    // 3) LayerNorm + exact GELU -> bf16 [b][n][c]
    ln_gelu_kernel<<<dim3(128, 8), 256, 0, stream>>>(cvo, ln_g, ln_b, gel);
    // 4) out = gelu @ proj_w^T + proj_b  (fp32 output; 768 blocks swizzled)
    gemm_tile<1><<<dim3(768), 256, 0, stream>>>(gel, projwb, nullptr, proj_b,
                                                nullptr, d_out);
}

// Round 8
// 270.036 us; speedup vs baseline: 1.0659x; 1.0659x over previous
//
#include <hip/hip_runtime.h>
#include <hip/hip_bf16.h>

typedef __hip_bfloat16 bf16;
typedef __attribute__((ext_vector_type(8))) short bfx8;
typedef __attribute__((ext_vector_type(4))) short bfx4;
typedef __attribute__((ext_vector_type(4))) float fx4;
typedef __attribute__((ext_vector_type(4))) int ix4;
typedef __attribute__((ext_vector_type(2))) int ix2;

#define KD 384
#define CH 384

__device__ __forceinline__ float bf2f(bf16 v) { return __bfloat162float(v); }
__device__ __forceinline__ bf16 f2bf(float v) { return __float2bfloat16(v); }
__device__ __forceinline__ int pk2(float x, float y) {
    return (int)(((unsigned)__bfloat16_as_ushort(__float2bfloat16(y)) << 16) |
                 (unsigned)__bfloat16_as_ushort(__float2bfloat16(x)));
}
__device__ __forceinline__ float lo16(int u) { return __uint_as_float((unsigned)u << 16); }
__device__ __forceinline__ float hi16(int u) { return __uint_as_float((unsigned)u & 0xffff0000u); }

typedef const __attribute__((address_space(1))) void gvoid;
typedef __attribute__((address_space(3))) void lvoid;
__device__ __forceinline__ void gload16(const void* g, void* l) {
    __builtin_amdgcn_global_load_lds((gvoid*)g, (lvoid*)l, 16, 0, 0);
}

// ---------------------------------------------------------------------------
// cast: fp32 -> bf16 for [x | q_w | kv_w | proj_w] into one contiguous span.
// ---------------------------------------------------------------------------
__global__ __launch_bounds__(256) void cast_kernel(
    const float* __restrict__ x, const float* __restrict__ qw,
    const float* __restrict__ kvw, const float* __restrict__ pw,
    bf16* __restrict__ dst)
{
    const int i = blockIdx.x * 256 + threadIdx.x;   // float4 index
    const float* s; int off;
    if (i < 3145728)      { s = x;   off = i; }
    else if (i < 3182592) { s = qw;  off = i - 3145728; }
    else if (i < 3256320) { s = kvw; off = i - 3182592; }
    else                  { s = pw;  off = i - 3256320; }
    const fx4 v = *(const fx4*)(s + (size_t)off * 4);
    const ix2 p = (ix2){pk2(v[0], v[1]), pk2(v[2], v[3])};
    *(ix2*)(void*)(dst + (size_t)i * 4) = p;
}

// ---------------------------------------------------------------------------
// GEMM (bf16, m97 structure): C[r,oc] = sum_k A[r,k]*B[oc,k] + bias[oc]
// MODE 0: B = [q_w;kv_w]; epilogue LDS-transpose -> qkv2[b][dd][t] bf16
// MODE 1: B = proj_w; fp32 store [r][oc] to d_out.
// 1-D grid, XCD-aware swizzle: all NT n-tiles of an m-tile map to the same
// XCD (f&7) consecutively -> A-tile fetched ~once instead of NT times.
// ---------------------------------------------------------------------------
template <int MODE>
__global__ __launch_bounds__(256) void gemm_tile(
    const bf16* __restrict__ A, const bf16* __restrict__ B0,
    const bf16* __restrict__ B1, const float* __restrict__ bias0,
    const float* __restrict__ bias1, void* __restrict__ outv)
{
    constexpr int NT = (MODE == 0) ? 9 : 3;
    const int tid  = threadIdx.x;
    const int wave = tid >> 6, lane = tid & 63;

    const int f = blockIdx.x;
    const int xcd = f & 7, idx = f >> 3;
    const int mi = idx / NT, nt = idx - mi * NT;
    const int m0 = (xcd + (mi << 3)) * 128;
    const int n0 = nt * 128;

    const bf16* Bsrc;
    const float* bsrc;
    int boff;
    if constexpr (MODE == 0) {
        if (n0 >= CH) { Bsrc = B1 + (size_t)(n0 - CH) * KD; bsrc = bias1; boff = n0 - CH; }
        else          { Bsrc = B0 + (size_t)n0 * KD;        bsrc = bias0; boff = n0; }
    } else {
        Bsrc = B0 + (size_t)n0 * KD; bsrc = bias0; boff = n0;
    }

    const int wm = (wave & 1) * 64, wn = (wave >> 1) * 64;
    const int r16 = lane & 15, quad = lane >> 4;
    const int sr = lane >> 2, sseg = lane & 3;

    // LDS union: K-loop uses As|Bs (16384 B); MODE0 epilogue reuses the same
    // space as tr[64*136] (17408 B). Live ranges separated by __syncthreads.
    constexpr int SMEM = (MODE == 0) ? 17408 : 16384;
    __shared__ __align__(16) char smem[SMEM];
    bf16* As = (bf16*)smem;             // 128*32
    bf16* Bs = (bf16*)(smem + 8192);    // 128*32

    fx4 acc[4][4];
#pragma unroll
    for (int i = 0; i < 4; ++i)
#pragma unroll
        for (int j = 0; j < 4; ++j) acc[i][j] = (fx4){0.f, 0.f, 0.f, 0.f};

    for (int kt = 0; kt < KD; kt += 32) {
        __syncthreads();
#pragma unroll
        for (int ii = 0; ii < 2; ++ii) {
            const int c = ii * 4 + wave;
            const int r = c * 16 + sr;
            gload16(A + (size_t)(m0 + r) * KD + kt + sseg * 8, (char*)As + c * 1024);
            gload16(Bsrc + (size_t)r * KD + kt + sseg * 8, (char*)Bs + c * 1024);
        }
        __syncthreads();   // vmcnt(0) drain: async loads landed

        bfx8 af[4], bfr[4];
#pragma unroll
        for (int t = 0; t < 4; ++t) {
            af[t]  = *(const bfx8*)(const void*)(As + (wm + t * 16 + r16) * 32 + quad * 8);
            bfr[t] = *(const bfx8*)(const void*)(Bs + (wn + t * 16 + r16) * 32 + quad * 8);
        }
#pragma unroll
        for (int i = 0; i < 4; ++i)
#pragma unroll
            for (int j = 0; j < 4; ++j)
                acc[i][j] = __builtin_amdgcn_mfma_f32_16x16x32_bf16(
                    af[i], bfr[j], acc[i][j], 0, 0, 0);
    }

    if constexpr (MODE == 0) {
        // epilogue: bias + transpose through LDS, store [b][dd][g][m] bf16
        bf16* tr = (bf16*)smem;   // 64*136 (overlays As/Bs; barrier-protected)
        const int bb = m0 >> 12, mbase = m0 & 4095;
#pragma unroll
        for (int half = 0; half < 2; ++half) {
            __syncthreads();   // prev readers (K-loop or half 0) done
            if ((wave >> 1) == half) {
#pragma unroll
                for (int j = 0; j < 4; ++j) {
                    const int ocl = j * 16 + r16;                 // 0..63 in half
                    const float bv = bsrc[boff + wn + j * 16 + r16];
#pragma unroll
                    for (int i = 0; i < 4; ++i) {
                        const int m_loc = wm + i * 16 + quad * 4;
                        const ix2 pr = (ix2){
                            pk2(acc[i][j][0] + bv, acc[i][j][1] + bv),
                            pk2(acc[i][j][2] + bv, acc[i][j][3] + bv)};
                        *(ix2*)(void*)(tr + ocl * 136 + m_loc) = pr;
                    }
                }
            }
            __syncthreads();
            bf16* outp = (bf16*)outv;
            for (int u = tid; u < 1024; u += 256) {
                const int ocl = u >> 4, seg = u & 15;
                const int oc = n0 + half * 64 + ocl;
                const int g = oc >> 6, dd = oc & 63;
                const ix4 val = *(const ix4*)(const void*)(tr + ocl * 136 + seg * 8);
                const size_t dst = (((size_t)(bb * 64 + dd)) * 18 + g) * 4096 + mbase + seg * 8;
                *(ix4*)(void*)(outp + dst) = val;
            }
        }
    } else {
#pragma unroll
        for (int j = 0; j < 4; ++j) {
            const int oc = n0 + wn + j * 16 + r16;
            const float bv = bsrc[boff + wn + j * 16 + r16];
#pragma unroll
            for (int i = 0; i < 4; ++i) {
#pragma unroll
                for (int v = 0; v < 4; ++v) {
                    const int r = m0 + wm + i * 16 + quad * 4 + v;
                    ((float*)outv)[(size_t)r * CH + oc] = acc[i][j][v] + bv;
                }
            }
        }
    }
}

// ---------------------------------------------------------------------------
// fused fc + grouped 3x3 conv.
// qkv2[b][dd][t] (t = n*18+i gives the 18 fc inputs of pixel n CONTIGUOUS).
// Per block (q,dd,b): fc into bf16 halo tile img[9][18][68], then 3x3 conv,
// 6 out channels, bf16 output cvo[b][oc384][n].
// ---------------------------------------------------------------------------
__global__ __launch_bounds__(256) void fcconv_kernel(
    const bf16* __restrict__ qkv2, const float* __restrict__ fc_w,
    const float* __restrict__ fc_b, const float* __restrict__ dep_w,
    const float* __restrict__ dep_b, bf16* __restrict__ cvo)
{
    const int tid = threadIdx.x;
    const int q = blockIdx.x, dd = blockIdx.y, b = blockIdx.z;
    const int h0 = q * 16;

    __shared__ bf16 img[9 * 18 * 68];   // 22032 B -> ~7 blocks/CU

    const bf16* qb = qkv2 + ((size_t)(b * 64 + dd)) * 73728;

    // ---- fc phase: 18 rows x 66 cols (halo) ----
    for (int p = tid; p < 18 * 66; p += 256) {
        const int r = p / 66, cc = p - r * 66;
        const int h = h0 - 1 + r, wg = cc - 1;
        float s[9];
        if (h >= 0 && h < 64 && wg >= 0 && wg < 64) {
            const int n = h * 64 + wg;
            const int* tp = (const int*)(const void*)(qb + (size_t)n * 18);
            float xv[18];
#pragma unroll
            for (int k = 0; k < 9; ++k) {
                const int u = tp[k];
                xv[2 * k]     = lo16(u);
                xv[2 * k + 1] = hi16(u);
            }
#pragma unroll
            for (int o = 0; o < 9; ++o) {
                float t = fc_b[o];
#pragma unroll
                for (int i = 0; i < 18; ++i) t += fc_w[o * 18 + i] * xv[i];
                s[o] = t;
            }
        } else {
#pragma unroll
            for (int o = 0; o < 9; ++o) s[o] = 0.f;
        }
#pragma unroll
        for (int o = 0; o < 9; ++o) img[(o * 18 + r) * 68 + cc] = f2bf(s[o]);
    }
    __syncthreads();

    // ---- conv phase ----
    const int r_out = tid >> 4;          // 0..15
    const int w0 = (tid & 15) * 4;       // 0..60

    float acc[6][4];
#pragma unroll
    for (int oc = 0; oc < 6; ++oc) {
        const float bv = dep_b[dd * 6 + oc];
#pragma unroll
        for (int k = 0; k < 4; ++k) acc[oc][k] = bv;
    }

    const float* wbase = dep_w + (size_t)dd * 486;
    for (int j = 0; j < 9; ++j) {
        float wj[6][9];
#pragma unroll
        for (int oc = 0; oc < 6; ++oc)
#pragma unroll
            for (int t = 0; t < 9; ++t) wj[oc][t] = wbase[oc * 81 + j * 9 + t];
#pragma unroll
        for (int dy = 0; dy < 3; ++dy) {
            const bf16* rp = img + (j * 18 + r_out + dy) * 68 + w0;
            const ix2 d01 = *(const ix2*)(const void*)rp;
            const int d2 = *(const int*)(const void*)(rp + 4);
            const float x0 = lo16(d01[0]), x1 = hi16(d01[0]);
            const float x2 = lo16(d01[1]), x3 = hi16(d01[1]);
            const float x4 = lo16(d2),     x5 = hi16(d2);
#pragma unroll
            for (int oc = 0; oc < 6; ++oc) {
                const float k0 = wj[oc][dy * 3], k1 = wj[oc][dy * 3 + 1], k2 = wj[oc][dy * 3 + 2];
                acc[oc][0] += k0 * x0 + k1 * x1 + k2 * x2;
                acc[oc][1] += k0 * x1 + k1 * x2 + k2 * x3;
                acc[oc][2] += k0 * x2 + k1 * x3 + k2 * x4;
                acc[oc][3] += k0 * x3 + k1 * x4 + k2 * x5;
            }
        }
    }

#pragma unroll
    for (int oc = 0; oc < 6; ++oc) {
        const size_t base =
            ((size_t)(b * 384 + dd * 6 + oc)) * 4096 + (h0 + r_out) * 64 + w0;
        const ix2 pr = (ix2){pk2(acc[oc][0], acc[oc][1]), pk2(acc[oc][2], acc[oc][3])};
        *(ix2*)(void*)(cvo + base) = pr;
    }
}

// ---------------------------------------------------------------------------
// LayerNorm over C + exact GELU; reads [b][oc][n] bf16, writes [b][n][c] bf16
// Loads vectorized 8 B/lane (ix2 = 4 bf16); stores packed 2×bf16 per int.
// ---------------------------------------------------------------------------
__global__ __launch_bounds__(256) void ln_gelu_kernel(
    const bf16* __restrict__ cvo, const float* __restrict__ ln_g,
    const float* __restrict__ ln_b, bf16* __restrict__ gel)
{
    const int tid = threadIdx.x;
    const int n0 = blockIdx.x * 32;
    const int b  = blockIdx.y;

    __shared__ float tile[384 * 33];
    __shared__ float ps[32 * 9], pq[32 * 9];
    __shared__ float mu_s[32], inv_s[32];

    const bf16* src = cvo + (size_t)b * 384 * 4096;
    for (int v = tid; v < 384 * 8; v += 256) {
        const int oc = v >> 3, j = v & 7;   // j indexes 4-wide n chunks
        const ix2 d = *(const ix2*)(const void*)(src + (size_t)oc * 4096 + n0 + j * 4);
        float* tp = tile + oc * 33 + j * 4;
        tp[0] = lo16(d[0]); tp[1] = hi16(d[0]);
        tp[2] = lo16(d[1]); tp[3] = hi16(d[1]);
    }
    __syncthreads();

    {
        const int nl = tid & 31, sl = tid >> 5;
        float s = 0.f, q = 0.f;
        for (int oc = sl * 48; oc < sl * 48 + 48; ++oc) {
            const float xv = tile[oc * 33 + nl];
            s += xv; q += xv * xv;
        }
        ps[nl * 9 + sl] = s; pq[nl * 9 + sl] = q;
    }
    __syncthreads();
    if (tid < 32) {
        float s = 0.f, q = 0.f;
        for (int k = 0; k < 8; ++k) { s += ps[tid * 9 + k]; q += pq[tid * 9 + k]; }
        const float mu = s * (1.f / 384.f);
        const float var = q * (1.f / 384.f) - mu * mu;
        mu_s[tid] = mu; inv_s[tid] = rsqrtf(var + 1e-5f);
    }
    __syncthreads();

    for (int v = tid; v < 192 * 32; v += 256) {
        const int oc2 = v % 192, nl = v / 192;
        const int oc = oc2 * 2;
        const float mu = mu_s[nl], inv = inv_s[nl];
        const float x0 = tile[oc * 33 + nl];
        const float x1 = tile[(oc + 1) * 33 + nl];
        const float y0 = (x0 - mu) * inv * ln_g[oc] + ln_b[oc];
        const float y1 = (x1 - mu) * inv * ln_g[oc + 1] + ln_b[oc + 1];
        const float g0 = 0.5f * y0 * (1.f + erff(y0 * 0.70710678118f));
        const float g1 = 0.5f * y1 * (1.f + erff(y1 * 0.70710678118f));
        *(int*)(void*)(gel + ((size_t)b * 4096 + n0 + nl) * 384 + oc) = pk2(g0, g1);
    }
}

// ---------------------------------------------------------------------------
extern "C" void kernel_launch(void* const* d_in, const int* in_sizes, int n_in,
                              void* d_out, int out_size, void* d_ws, size_t ws_size,
                              hipStream_t stream)
{
    const float* x      = (const float*)d_in[0];
    const float* q_w    = (const float*)d_in[1];
    const float* q_b    = (const float*)d_in[2];
    const float* kv_w   = (const float*)d_in[3];
    const float* kv_b   = (const float*)d_in[4];
    const float* fc_w   = (const float*)d_in[5];
    const float* fc_b   = (const float*)d_in[6];
    const float* dep_w  = (const float*)d_in[7];
    const float* dep_b  = (const float*)d_in[8];
    const float* ln_g   = (const float*)d_in[9];
    const float* ln_b   = (const float*)d_in[10];
    const float* proj_w = (const float*)d_in[11];
    const float* proj_b = (const float*)d_in[12];

    // workspace (total 152,174,592 B):
    char* ws = (char*)d_ws;
    bf16*  castspan = (bf16*)ws;                    // 26,345,472 B
    bf16*  xb     = castspan;
    bf16*  qwb    = castspan + 12582912;
    bf16*  kvwb   = castspan + 12730368;
    bf16*  projwb = castspan + 13025280;
    bf16*  qkv2   = (bf16*)(ws + 26345472);         // 75,497,472 B  [b][dd][t]
    bf16*  cvo    = (bf16*)(ws + 101842944);        // 25,165,824 B  [b][oc][n]
    bf16*  gel    = (bf16*)(ws + 127008768);        // 25,165,824 B  [b][n][c]

    // 0) fp32 -> bf16 cast of x and the GEMM weight matrices
    cast_kernel<<<dim3(12864), 256, 0, stream>>>(x, q_w, kv_w, proj_w, castspan);
    // 1) qkv2 = X @ [q_w;kv_w]^T + bias, transposed store [b][dd][t]
    gemm_tile<0><<<dim3(2304), 256, 0, stream>>>(xb, qwb, kvwb, q_b, kv_b, qkv2);
    // 2) fused fc + grouped 3x3 conv -> bf16 [b][oc][n]
    fcconv_kernel<<<dim3(4, 64, 8), 256, 0, stream>>>(qkv2, fc_w, fc_b, dep_w,
                                                      dep_b, cvo);
    // 3) LayerNorm + exact GELU -> bf16 [b][n][c]
    ln_gelu_kernel<<<dim3(128, 8), 256, 0, stream>>>(cvo, ln_g, ln_b, gel);
    // 4) out = gelu @ proj_w^T + proj_b  (fp32 output; 768 blocks swizzled)
    gemm_tile<1><<<dim3(768), 256, 0, stream>>>(gel, projwb, nullptr, proj_b,
                                                nullptr, d_out);
}

// Round 12
// 262.126 us; speedup vs baseline: 1.0981x; 1.0302x over previous
//
#include <hip/hip_runtime.h>
#include <hip/hip_bf16.h>

typedef __hip_bfloat16 bf16;
typedef __attribute__((ext_vector_type(8))) short bfx8;
typedef __attribute__((ext_vector_type(4))) short bfx4;
typedef __attribute__((ext_vector_type(4))) float fx4;
typedef __attribute__((ext_vector_type(4))) int ix4;
typedef __attribute__((ext_vector_type(2))) int ix2;

#define KD 384
#define CH 384

__device__ __forceinline__ float bf2f(bf16 v) { return __bfloat162float(v); }
__device__ __forceinline__ bf16 f2bf(float v) { return __float2bfloat16(v); }
__device__ __forceinline__ int pk2(float x, float y) {
    return (int)(((unsigned)__bfloat16_as_ushort(__float2bfloat16(y)) << 16) |
                 (unsigned)__bfloat16_as_ushort(__float2bfloat16(x)));
}
__device__ __forceinline__ float lo16(int u) { return __uint_as_float((unsigned)u << 16); }
__device__ __forceinline__ float hi16(int u) { return __uint_as_float((unsigned)u & 0xffff0000u); }

typedef const __attribute__((address_space(1))) void gvoid;
typedef __attribute__((address_space(3))) void lvoid;
__device__ __forceinline__ void gload16(const void* g, void* l) {
    __builtin_amdgcn_global_load_lds((gvoid*)g, (lvoid*)l, 16, 0, 0);
}

// ---------------------------------------------------------------------------
// cast: fp32 -> bf16 for [x | q_w | kv_w | proj_w] into one contiguous span.
// ---------------------------------------------------------------------------
__global__ __launch_bounds__(256) void cast_kernel(
    const float* __restrict__ x, const float* __restrict__ qw,
    const float* __restrict__ kvw, const float* __restrict__ pw,
    bf16* __restrict__ dst)
{
    const int i = blockIdx.x * 256 + threadIdx.x;   // float4 index
    const float* s; int off;
    if (i < 3145728)      { s = x;   off = i; }
    else if (i < 3182592) { s = qw;  off = i - 3145728; }
    else if (i < 3256320) { s = kvw; off = i - 3182592; }
    else                  { s = pw;  off = i - 3256320; }
    const fx4 v = *(const fx4*)(s + (size_t)off * 4);
    const ix2 p = (ix2){pk2(v[0], v[1]), pk2(v[2], v[3])};
    *(ix2*)(void*)(dst + (size_t)i * 4) = p;
}

// ---------------------------------------------------------------------------
// GEMM (bf16, m97 structure): C[r,oc] = sum_k A[r,k]*B[oc,k] + bias[oc]
// MODE 0: B = [q_w;kv_w]; epilogue LDS-transpose -> qkv2[b][dd][t] bf16
// MODE 1: B = proj_w; fp32 store [r][oc] to d_out.
// ---------------------------------------------------------------------------
template <int MODE>
__global__ __launch_bounds__(256) void gemm_tile(
    const bf16* __restrict__ A, const bf16* __restrict__ B0,
    const bf16* __restrict__ B1, const float* __restrict__ bias0,
    const float* __restrict__ bias1, void* __restrict__ outv)
{
    constexpr int NT = (MODE == 0) ? 9 : 3;
    const int tid  = threadIdx.x;
    const int wave = tid >> 6, lane = tid & 63;

    const int f = blockIdx.x;
    const int xcd = f & 7, idx = f >> 3;
    const int mi = idx / NT, nt = idx - mi * NT;
    const int m0 = (xcd + (mi << 3)) * 128;
    const int n0 = nt * 128;

    const bf16* Bsrc;
    const float* bsrc;
    int boff;
    if constexpr (MODE == 0) {
        if (n0 >= CH) { Bsrc = B1 + (size_t)(n0 - CH) * KD; bsrc = bias1; boff = n0 - CH; }
        else          { Bsrc = B0 + (size_t)n0 * KD;        bsrc = bias0; boff = n0; }
    } else {
        Bsrc = B0 + (size_t)n0 * KD; bsrc = bias0; boff = n0;
    }

    const int wm = (wave & 1) * 64, wn = (wave >> 1) * 64;
    const int r16 = lane & 15, quad = lane >> 4;
    const int sr = lane >> 2, sseg = lane & 3;

    constexpr int SMEM = (MODE == 0) ? 17408 : 16384;
    __shared__ __align__(16) char smem[SMEM];
    bf16* As = (bf16*)smem;             // 128*32
    bf16* Bs = (bf16*)(smem + 8192);    // 128*32

    fx4 acc[4][4];
#pragma unroll
    for (int i = 0; i < 4; ++i)
#pragma unroll
        for (int j = 0; j < 4; ++j) acc[i][j] = (fx4){0.f, 0.f, 0.f, 0.f};

    for (int kt = 0; kt < KD; kt += 32) {
        __syncthreads();
#pragma unroll
        for (int ii = 0; ii < 2; ++ii) {
            const int c = ii * 4 + wave;
            const int r = c * 16 + sr;
            gload16(A + (size_t)(m0 + r) * KD + kt + sseg * 8, (char*)As + c * 1024);
            gload16(Bsrc + (size_t)r * KD + kt + sseg * 8, (char*)Bs + c * 1024);
        }
        __syncthreads();   // vmcnt(0) drain: async loads landed

        bfx8 af[4], bfr[4];
#pragma unroll
        for (int t = 0; t < 4; ++t) {
            af[t]  = *(const bfx8*)(const void*)(As + (wm + t * 16 + r16) * 32 + quad * 8);
            bfr[t] = *(const bfx8*)(const void*)(Bs + (wn + t * 16 + r16) * 32 + quad * 8);
        }
#pragma unroll
        for (int i = 0; i < 4; ++i)
#pragma unroll
            for (int j = 0; j < 4; ++j)
                acc[i][j] = __builtin_amdgcn_mfma_f32_16x16x32_bf16(
                    af[i], bfr[j], acc[i][j], 0, 0, 0);
    }

    if constexpr (MODE == 0) {
        // epilogue: bias + transpose through LDS, store [b][dd][g][m] bf16
        bf16* tr = (bf16*)smem;   // 64*136 (overlays As/Bs; barrier-protected)
        const int bb = m0 >> 12, mbase = m0 & 4095;
#pragma unroll
        for (int half = 0; half < 2; ++half) {
            __syncthreads();   // prev readers (K-loop or half 0) done
            if ((wave >> 1) == half) {
#pragma unroll
                for (int j = 0; j < 4; ++j) {
                    const int ocl = j * 16 + r16;                 // 0..63 in half
                    const float bv = bsrc[boff + wn + j * 16 + r16];
#pragma unroll
                    for (int i = 0; i < 4; ++i) {
                        const int m_loc = wm + i * 16 + quad * 4;
                        const ix2 pr = (ix2){
                            pk2(acc[i][j][0] + bv, acc[i][j][1] + bv),
                            pk2(acc[i][j][2] + bv, acc[i][j][3] + bv)};
                        *(ix2*)(void*)(tr + ocl * 136 + m_loc) = pr;
                    }
                }
            }
            __syncthreads();
            bf16* outp = (bf16*)outv;
            for (int u = tid; u < 1024; u += 256) {
                const int ocl = u >> 4, seg = u & 15;
                const int oc = n0 + half * 64 + ocl;
                const int g = oc >> 6, dd = oc & 63;
                const ix4 val = *(const ix4*)(const void*)(tr + ocl * 136 + seg * 8);
                const size_t dst = (((size_t)(bb * 64 + dd)) * 18 + g) * 4096 + mbase + seg * 8;
                *(ix4*)(void*)(outp + dst) = val;
            }
        }
    } else {
#pragma unroll
        for (int j = 0; j < 4; ++j) {
            const int oc = n0 + wn + j * 16 + r16;
            const float bv = bsrc[boff + wn + j * 16 + r16];
#pragma unroll
            for (int i = 0; i < 4; ++i) {
#pragma unroll
                for (int v = 0; v < 4; ++v) {
                    const int r = m0 + wm + i * 16 + quad * 4 + v;
                    ((float*)outv)[(size_t)r * CH + oc] = acc[i][j][v] + bv;
                }
            }
        }
    }
}

// ---------------------------------------------------------------------------
// fused fc + grouped 3x3 conv.
// fc phase: UNCHANGED from the verified 270 µs kernel (scalar, fp32 weights).
// conv phase: MFMA 16x16x32 bf16. Per dd: out[6][px] = W[6x81]·patch.
// Decomposed per dx (3 MFMAs, K=32 >= 27 (j,dy) taps, one chained fx4 acc).
// Fragment layouts identical to gemm_tile's verified usage:
//   A-frag: row = lane&15 (=oc, zero-padded >=6), k = quad*8+e (zero >=27)
//   B-frag: col = lane&15 (=pixel), k = quad*8+e; LDS offsets precomputed
//   C:      row = quad*4+reg (=oc), col = lane&15 (=pixel)
// Zero A rows/cols annihilate garbage B reads -> no B masking needed.
// ---------------------------------------------------------------------------
__global__ __launch_bounds__(256) void fcconv_kernel(
    const bf16* __restrict__ qkv2, const float* __restrict__ fc_w,
    const float* __restrict__ fc_b, const float* __restrict__ dep_w,
    const float* __restrict__ dep_b, bf16* __restrict__ cvo)
{
    const int tid = threadIdx.x;
    const int q = blockIdx.x, dd = blockIdx.y, b = blockIdx.z;
    const int h0 = q * 16;

    __shared__ bf16 img[9 * 18 * 68];   // 22032 B

    const bf16* qb = qkv2 + ((size_t)(b * 64 + dd)) * 73728;

    // ---- fc phase: 18 rows x 66 cols (halo) -- UNCHANGED ----
    for (int p = tid; p < 18 * 66; p += 256) {
        const int r = p / 66, cc = p - r * 66;
        const int h = h0 - 1 + r, wg = cc - 1;
        float s[9];
        if (h >= 0 && h < 64 && wg >= 0 && wg < 64) {
            const int n = h * 64 + wg;
            const int* tp = (const int*)(const void*)(qb + (size_t)n * 18);
            float xv[18];
#pragma unroll
            for (int k = 0; k < 9; ++k) {
                const int u = tp[k];
                xv[2 * k]     = lo16(u);
                xv[2 * k + 1] = hi16(u);
            }
#pragma unroll
            for (int o = 0; o < 9; ++o) {
                float t = fc_b[o];
#pragma unroll
                for (int i = 0; i < 18; ++i) t += fc_w[o * 18 + i] * xv[i];
                s[o] = t;
            }
        } else {
#pragma unroll
            for (int o = 0; o < 9; ++o) s[o] = 0.f;
        }
#pragma unroll
        for (int o = 0; o < 9; ++o) img[(o * 18 + r) * 68 + cc] = f2bf(s[o]);
    }
    __syncthreads();

    // ---- conv phase: MFMA ----
    const int wave = tid >> 6, lane = tid & 63;
    const int col = lane & 15, quad = lane >> 4;

    // A-frags, one per dx. k = quad*8+e maps to (j = k/3, dy = k%3), k<27.
    // Runtime div OK here: prologue, once per block.
    bfx8 af3[3];
    int joff[8];                         // LDS element offset of (j,dy) per e
    {
        const float* wsrc = dep_w + (size_t)dd * 486 + (size_t)col * 81;
#pragma unroll
        for (int dx = 0; dx < 3; ++dx) {
            short tmp[8];
#pragma unroll
            for (int e = 0; e < 8; ++e) {
                const int k = quad * 8 + e;
                const int j = k / 3, dy = k - j * 3;
                float v = 0.f;
                if (col < 6 && k < 27) v = wsrc[j * 9 + dy * 3 + dx];
                tmp[e] = (short)__bfloat16_as_ushort(f2bf(v));
                if (dx == 0) joff[e] = (k < 27) ? (j * 1224 + dy * 68) : 0;
            }
            af3[dx] = (bfx8){tmp[0], tmp[1], tmp[2], tmp[3],
                             tmp[4], tmp[5], tmp[6], tmp[7]};
        }
    }
    float fb[4];
#pragma unroll
    for (int i = 0; i < 4; ++i) {
        const int oc = quad * 4 + i;
        fb[i] = (oc < 6) ? dep_b[dd * 6 + oc] : 0.f;
    }

    const unsigned short* img_s = (const unsigned short*)(const void*)img;
    bf16* outb = cvo + ((size_t)(b * 384 + dd * 6)) * 4096;

    // 64 tiles: rr in [0,16) x wg in [0,4); wave-strided.
    for (int t = wave; t < 64; t += 4) {
        const int rr = t >> 2, wg2 = t & 3;
        const int w = wg2 * 16 + col;
        const int base = rr * 68 + w;
        int ve[8];
#pragma unroll
        for (int e = 0; e < 8; ++e) ve[e] = base + joff[e];

        fx4 acc = (fx4){0.f, 0.f, 0.f, 0.f};
#pragma unroll
        for (int dx = 0; dx < 3; ++dx) {
            short tmp[8];
#pragma unroll
            for (int e = 0; e < 8; ++e) tmp[e] = (short)img_s[ve[e] + dx];
            const bfx8 bfrag = (bfx8){tmp[0], tmp[1], tmp[2], tmp[3],
                                      tmp[4], tmp[5], tmp[6], tmp[7]};
            acc = __builtin_amdgcn_mfma_f32_16x16x32_bf16(af3[dx], bfrag, acc,
                                                          0, 0, 0);
        }

        const int n = (h0 + rr) * 64 + w;
#pragma unroll
        for (int i = 0; i < 4; ++i) {
            const int oc = quad * 4 + i;
            if (oc < 6) outb[(size_t)oc * 4096 + n] = f2bf(acc[i] + fb[i]);
        }
    }
}

// ---------------------------------------------------------------------------
// LayerNorm over C + exact GELU; reads [b][oc][n] bf16, writes [b][n][c] bf16
// ---------------------------------------------------------------------------
__global__ __launch_bounds__(256) void ln_gelu_kernel(
    const bf16* __restrict__ cvo, const float* __restrict__ ln_g,
    const float* __restrict__ ln_b, bf16* __restrict__ gel)
{
    const int tid = threadIdx.x;
    const int n0 = blockIdx.x * 32;
    const int b  = blockIdx.y;

    __shared__ float tile[384 * 33];
    __shared__ float ps[32 * 9], pq[32 * 9];
    __shared__ float mu_s[32], inv_s[32];

    const bf16* src = cvo + (size_t)b * 384 * 4096;
    for (int v = tid; v < 384 * 8; v += 256) {
        const int oc = v >> 3, j = v & 7;   // j indexes 4-wide n chunks
        const ix2 d = *(const ix2*)(const void*)(src + (size_t)oc * 4096 + n0 + j * 4);
        float* tp = tile + oc * 33 + j * 4;
        tp[0] = lo16(d[0]); tp[1] = hi16(d[0]);
        tp[2] = lo16(d[1]); tp[3] = hi16(d[1]);
    }
    __syncthreads();

    {
        const int nl = tid & 31, sl = tid >> 5;
        float s = 0.f, q = 0.f;
        for (int oc = sl * 48; oc < sl * 48 + 48; ++oc) {
            const float xv = tile[oc * 33 + nl];
            s += xv; q += xv * xv;
        }
        ps[nl * 9 + sl] = s; pq[nl * 9 + sl] = q;
    }
    __syncthreads();
    if (tid < 32) {
        float s = 0.f, q = 0.f;
        for (int k = 0; k < 8; ++k) { s += ps[tid * 9 + k]; q += pq[tid * 9 + k]; }
        const float mu = s * (1.f / 384.f);
        const float var = q * (1.f / 384.f) - mu * mu;
        mu_s[tid] = mu; inv_s[tid] = rsqrtf(var + 1e-5f);
    }
    __syncthreads();

    for (int v = tid; v < 192 * 32; v += 256) {
        const int oc2 = v % 192, nl = v / 192;
        const int oc = oc2 * 2;
        const float mu = mu_s[nl], inv = inv_s[nl];
        const float x0 = tile[oc * 33 + nl];
        const float x1 = tile[(oc + 1) * 33 + nl];
        const float y0 = (x0 - mu) * inv * ln_g[oc] + ln_b[oc];
        const float y1 = (x1 - mu) * inv * ln_g[oc + 1] + ln_b[oc + 1];
        const float g0 = 0.5f * y0 * (1.f + erff(y0 * 0.70710678118f));
        const float g1 = 0.5f * y1 * (1.f + erff(y1 * 0.70710678118f));
        *(int*)(void*)(gel + ((size_t)b * 4096 + n0 + nl) * 384 + oc) = pk2(g0, g1);
    }
}

// ---------------------------------------------------------------------------
extern "C" void kernel_launch(void* const* d_in, const int* in_sizes, int n_in,
                              void* d_out, int out_size, void* d_ws, size_t ws_size,
                              hipStream_t stream)
{
    const float* x      = (const float*)d_in[0];
    const float* q_w    = (const float*)d_in[1];
    const float* q_b    = (const float*)d_in[2];
    const float* kv_w   = (const float*)d_in[3];
    const float* kv_b   = (const float*)d_in[4];
    const float* fc_w   = (const float*)d_in[5];
    const float* fc_b   = (const float*)d_in[6];
    const float* dep_w  = (const float*)d_in[7];
    const float* dep_b  = (const float*)d_in[8];
    const float* ln_g   = (const float*)d_in[9];
    const float* ln_b   = (const float*)d_in[10];
    const float* proj_w = (const float*)d_in[11];
    const float* proj_b = (const float*)d_in[12];

    // workspace (total 152,174,592 B):
    char* ws = (char*)d_ws;
    bf16*  castspan = (bf16*)ws;                    // 26,345,472 B
    bf16*  xb     = castspan;
    bf16*  qwb    = castspan + 12582912;
    bf16*  kvwb   = castspan + 12730368;
    bf16*  projwb = castspan + 13025280;
    bf16*  qkv2   = (bf16*)(ws + 26345472);         // 75,497,472 B  [b][dd][t]
    bf16*  cvo    = (bf16*)(ws + 101842944);        // 25,165,824 B  [b][oc][n]
    bf16*  gel    = (bf16*)(ws + 127008768);        // 25,165,824 B  [b][n][c]

    // 0) fp32 -> bf16 cast of x and the GEMM weight matrices
    cast_kernel<<<dim3(12864), 256, 0, stream>>>(x, q_w, kv_w, proj_w, castspan);
    // 1) qkv2 = X @ [q_w;kv_w]^T + bias, transposed store [b][dd][t]
    gemm_tile<0><<<dim3(2304), 256, 0, stream>>>(xb, qwb, kvwb, q_b, kv_b, qkv2);
    // 2) fused fc + grouped 3x3 conv (MFMA conv) -> bf16 [b][oc][n]
    fcconv_kernel<<<dim3(4, 64, 8), 256, 0, stream>>>(qkv2, fc_w, fc_b, dep_w,
                                                      dep_b, cvo);
    // 3) LayerNorm + exact GELU -> bf16 [b][n][c]
    ln_gelu_kernel<<<dim3(128, 8), 256, 0, stream>>>(cvo, ln_g, ln_b, gel);
    // 4) out = gelu @ proj_w^T + proj_b  (fp32 output; 768 blocks swizzled)
    gemm_tile<1><<<dim3(768), 256, 0, stream>>>(gel, projwb, nullptr, proj_b,
                                                nullptr, d_out);
}